// Round 4
// baseline (112.700 us; speedup 1.0000x reference)
//
#include <hip/hip_runtime.h>
#include <math.h>

#define HH 512
#define WW 512
#define NB 8
#define NN 256
#define KR 6
#define KS 13

__device__ __forceinline__ float bilerp_img(const float* __restrict__ img, float r, float c) {
    r = fminf(fmaxf(r, 0.f), (float)(HH - 1));
    c = fminf(fmaxf(c, 0.f), (float)(WW - 1));
    float rf = floorf(r), cf = floorf(c);
    int r0 = (int)rf, c0 = (int)cf;
    int r1 = min(r0 + 1, HH - 1), c1 = min(c0 + 1, WW - 1);
    float fr = r - rf, fc = c - cf;
    float v00 = img[r0 * WW + c0];
    float v01 = img[r0 * WW + c1];
    float v10 = img[r1 * WW + c0];
    float v11 = img[r1 * WW + c1];
    return v00 * (1.f - fr) * (1.f - fc) + v10 * fr * (1.f - fc)
         + v01 * (1.f - fr) * fc + v11 * fr * fc;
}

// ---------------- conv: separable 13x13 Gaussian-derivative, x10 ----------------
__global__ __launch_bounds__(256) void conv_kernel(const float* __restrict__ pred,
                                                   float* __restrict__ gimg) {
    __shared__ float tin[32 + 2 * KR][32 + 2 * KR];   // 44x44
    __shared__ float midG[32 + 2 * KR][32];
    __shared__ float midD[32 + 2 * KR][32];

    const int b  = blockIdx.z;
    const int ty0 = blockIdx.y * 32;
    const int tx0 = blockIdx.x * 32;
    const int t  = threadIdx.x;

    float g[KS], dg[KS];
    float s = 0.f;
#pragma unroll
    for (int i = 0; i < KS; ++i) {
        float x = (float)(i - KR);
        g[i] = expf(-x * x / 8.f);  // std=2 -> 2*std^2 = 8
        s += g[i];
    }
#pragma unroll
    for (int i = 0; i < KS; ++i) {
        g[i] /= s;
        dg[i] = (-(float)(i - KR) / 4.f) * g[i];
    }

    const float* img = pred + (size_t)b * HH * WW;

    for (int idx = t; idx < 44 * 44; idx += 256) {
        int ly = idx / 44, lx = idx % 44;
        int gy = ty0 + ly - KR, gx = tx0 + lx - KR;
        float v = 0.f;
        if (gy >= 0 && gy < HH && gx >= 0 && gx < WW) v = img[gy * WW + gx];
        tin[ly][lx] = v;
    }
    __syncthreads();

    for (int idx = t; idx < 44 * 32; idx += 256) {
        int ly = idx / 32, ox = idx % 32;
        float aG = 0.f, aD = 0.f;
#pragma unroll
        for (int k = 0; k < KS; ++k) {
            float v = tin[ly][ox + k];
            aG += v * g[k];
            aD += v * dg[k];
        }
        midG[ly][ox] = aG;
        midD[ly][ox] = aD;
    }
    __syncthreads();

    float* out0 = gimg + ((size_t)b * 2 + 0) * HH * WW;
    float* out1 = gimg + ((size_t)b * 2 + 1) * HH * WW;
    for (int idx = t; idx < 32 * 32; idx += 256) {
        int oy = idx / 32, ox = idx % 32;
        float a0 = 0.f, a1 = 0.f;
#pragma unroll
        for (int k = 0; k < KS; ++k) {
            a0 += midG[oy + k][ox] * dg[k];
            a1 += midD[oy + k][ox] * g[k];
        }
        int gy = ty0 + oy, gx = tx0 + ox;
        out0[gy * WW + gx] = 10.f * a0;
        out1[gy * WW + gx] = 10.f * a1;
    }
}

// ---------------- snake optimization: 20 implicit steps, 1 wave per batch ----------------
// 64 lanes x 4 nodes/lane, all state in registers. Pentadiagonal Neumann
// iterations exchange +-2 neighbors via __shfl (no barriers, no LDS).
// M*q = q - Xq + X^2 q - X^3 q + X^4 q, ||X|| <= 0.02 -> truncation ~3e-9 rel.
__global__ __launch_bounds__(64) void snake_kernel(const float* __restrict__ gimg,
                                                   const float* __restrict__ node_pos,
                                                   float* __restrict__ pos_out) {
    const int b = blockIdx.x;
    const int l = threadIdx.x;   // lane, nodes 4l..4l+3
    const float* g0 = gimg + (size_t)b * 2 * HH * WW;
    const float* g1 = g0 + (size_t)HH * WW;

    // load 4 nodes (8 contiguous floats)
    const float4* np4 = (const float4*)(node_pos + (size_t)(b * NN + 4 * l) * 2);
    float4 na = np4[0], nb = np4[1];
    float p0[4] = {na.x, na.z, nb.x, nb.z};
    float p1[4] = {na.y, na.w, nb.y, nb.w};

    // pentadiagonal rows of X for the 4 nodes
    auto Dv = [](int i, int j) -> float {
        if (i < 0 || i >= NN || j < 0 || j >= NN) return 0.f;
        if (i == j) return (i == 0 || i == NN - 1) ? 1.f : 2.f;
        int d = i - j;
        if (d == 1 || d == -1) return -1.f;
        return 0.f;
    };
    float xc[4][5];
#pragma unroll
    for (int i = 0; i < 4; ++i) {
        int n = 4 * l + i;
#pragma unroll
        for (int dj = -2; dj <= 2; ++dj) {
            int j = n + dj;
            float d2 = 0.f;
#pragma unroll
            for (int kk = -1; kk <= 1; ++kk) d2 += Dv(n, n + kk) * Dv(n + kk, j);
            xc[i][dj + 2] = 0.1f * (0.01f * Dv(n, j) + 0.01f * d2);
        }
    }

    for (int step = 0; step < 20; ++step) {
        float q0[4], q1[4], s0[4], s1[4];
#pragma unroll
        for (int i = 0; i < 4; ++i) {
            float f0 = bilerp_img(g0, p0[i], p1[i]);
            float f1 = bilerp_img(g1, p0[i], p1[i]);
            q0[i] = p0[i] + 0.1f * f0;
            q1[i] = p1[i] + 0.1f * f1;
            s0[i] = q0[i];
            s1[i] = q1[i];
        }
#pragma unroll
        for (int it = 0; it < 4; ++it) {
            // neighbor slots n0/n1[j] = s[4l-2+j], j=0..7 (boundary lanes get own
            // values back from shfl; multiplied by zero coefficients -> exact)
            float n0[8], n1[8];
            n0[0] = __shfl_up(s0[2], 1);   n0[1] = __shfl_up(s0[3], 1);
            n1[0] = __shfl_up(s1[2], 1);   n1[1] = __shfl_up(s1[3], 1);
            n0[6] = __shfl_down(s0[0], 1); n0[7] = __shfl_down(s0[1], 1);
            n1[6] = __shfl_down(s1[0], 1); n1[7] = __shfl_down(s1[1], 1);
#pragma unroll
            for (int i = 0; i < 4; ++i) { n0[2 + i] = s0[i]; n1[2 + i] = s1[i]; }
            float t0[4], t1[4];
#pragma unroll
            for (int i = 0; i < 4; ++i) {
                float a0 = 0.f, a1 = 0.f;
#pragma unroll
                for (int k = 0; k < 5; ++k) {
                    a0 += xc[i][k] * n0[i + k];
                    a1 += xc[i][k] * n1[i + k];
                }
                t0[i] = q0[i] - a0;
                t1[i] = q1[i] - a1;
            }
#pragma unroll
            for (int i = 0; i < 4; ++i) { s0[i] = t0[i]; s1[i] = t1[i]; }
        }
#pragma unroll
        for (int i = 0; i < 4; ++i) {
            p0[i] = fminf(fmaxf(s0[i], 0.f), (float)(HH - 1));
            p1[i] = fminf(fmaxf(s1[i], 0.f), (float)(WW - 1));
        }
    }

    float4 o1 = {p0[0], p1[0], p0[1], p1[1]};
    float4 o2 = {p0[2], p1[2], p0[3], p1[3]};
    float4* op = (float4*)(pos_out + (size_t)(b * NN + 4 * l) * 2);
    op[0] = o1;
    op[1] = o2;
}

// ---------------- render distance map + MSE loss (tile-binned) ----------------
__global__ __launch_bounds__(256) void render_loss_kernel(const float* __restrict__ pred,
                                                          const float* __restrict__ pos,
                                                          const float* __restrict__ widths,
                                                          float* __restrict__ out) {
    __shared__ float sl0[NN], sl1[NN], slw[NN];
    __shared__ int cnt;
    __shared__ float red[256];

    const int b    = blockIdx.x >> 8;        // 256 tiles (16x16) per batch
    const int tile = blockIdx.x & 255;
    const int ty0  = (tile >> 4) * 32;
    const int tx0  = (tile & 15) * 32;
    const int t    = threadIdx.x;

    if (t == 0) cnt = 0;
    __syncthreads();

    {   // node t relevance test against dilated tile box
        float p0 = pos[(b * NN + t) * 2 + 0];
        float p1 = pos[(b * NN + t) * 2 + 1];
        float w  = widths[b * NN + t];
        float dy = fmaxf(fmaxf((float)ty0 - p0, p0 - (float)(ty0 + 31)), 0.f);
        float dx = fmaxf(fmaxf((float)tx0 - p1, p1 - (float)(tx0 + 31)), 0.f);
        float rr = 15.f + w;
        if (dy * dy + dx * dx <= rr * rr) {
            int i = atomicAdd(&cnt, 1);
            sl0[i] = p0; sl1[i] = p1; slw[i] = w;
        }
    }
    __syncthreads();
    const int c = cnt;

    const float* pimg = pred + (size_t)b * HH * WW;
    float acc = 0.f;
#pragma unroll
    for (int i = 0; i < 4; ++i) {
        int idx = i * 256 + t;               // pixel within tile
        int oy = idx >> 5, ox = idx & 31;
        float fy = (float)(ty0 + oy);
        float fx = (float)(tx0 + ox);
        float dm = 15.0f;
        for (int j = 0; j < c; ++j) {
            float dy = fy - sl0[j];
            float dx = fx - sl1[j];
            float d = __builtin_amdgcn_sqrtf(dy * dy + dx * dx) - slw[j];
            dm = fminf(dm, d);
        }
        dm = fminf(fmaxf(dm, 0.f), 15.0f);
        float e = pimg[(ty0 + oy) * WW + (tx0 + ox)] - dm;
        acc += e * e;
    }

    red[t] = acc * (1.0f / (float)(NB * HH * WW));
    __syncthreads();
#pragma unroll
    for (int s = 128; s > 0; s >>= 1) {
        if (t < s) red[t] += red[t + s];
        __syncthreads();
    }
    if (t == 0) atomicAdd(out, red[0]);
}

extern "C" void kernel_launch(void* const* d_in, const int* in_sizes, int n_in,
                              void* d_out, int out_size, void* d_ws, size_t ws_size,
                              hipStream_t stream) {
    const float* pred     = (const float*)d_in[0];  // [8,1,512,512]
    const float* node_pos = (const float*)d_in[1];  // [8,256,2]
    const float* widths   = (const float*)d_in[2];  // [8,256]
    float* out = (float*)d_out;

    float* gimg    = (float*)d_ws;                          // [8][2][512][512] = 16 MB
    float* pos_out = gimg + (size_t)NB * 2 * HH * WW;       // [8][256][2]

    (void)hipMemsetAsync(out, 0, sizeof(float), stream);

    dim3 cgrid(WW / 32, HH / 32, NB);
    conv_kernel<<<cgrid, 256, 0, stream>>>(pred, gimg);

    snake_kernel<<<NB, 64, 0, stream>>>(gimg, node_pos, pos_out);

    render_loss_kernel<<<NB * 256, 256, 0, stream>>>(pred, pos_out, widths, out);
}

// Round 5
// 92.830 us; speedup vs baseline: 1.2140x; 1.2140x over previous
//
#include <hip/hip_runtime.h>
#include <math.h>

#define HH 512
#define WW 512
#define NB 8
#define NN 256
#define KR 6
#define KS 13

// ---------------- conv: separable 13x13 Gaussian-derivative, x10 ----------------
// Writes gimg interleaved as float2 (ch0, ch1) per pixel so snake's bilerp
// fetches both channels with one dwordx2 load.
__global__ __launch_bounds__(256) void conv_kernel(const float* __restrict__ pred,
                                                   float2* __restrict__ gimg2) {
    __shared__ float tin[32 + 2 * KR][32 + 2 * KR];   // 44x44
    __shared__ float midG[32 + 2 * KR][32];
    __shared__ float midD[32 + 2 * KR][32];

    const int b  = blockIdx.z;
    const int ty0 = blockIdx.y * 32;
    const int tx0 = blockIdx.x * 32;
    const int t  = threadIdx.x;

    float g[KS], dg[KS];
    float s = 0.f;
#pragma unroll
    for (int i = 0; i < KS; ++i) {
        float x = (float)(i - KR);
        g[i] = expf(-x * x / 8.f);  // std=2 -> 2*std^2 = 8
        s += g[i];
    }
#pragma unroll
    for (int i = 0; i < KS; ++i) {
        g[i] /= s;
        dg[i] = (-(float)(i - KR) / 4.f) * g[i];
    }

    const float* img = pred + (size_t)b * HH * WW;

    for (int idx = t; idx < 44 * 44; idx += 256) {
        int ly = idx / 44, lx = idx % 44;
        int gy = ty0 + ly - KR, gx = tx0 + lx - KR;
        float v = 0.f;
        if (gy >= 0 && gy < HH && gx >= 0 && gx < WW) v = img[gy * WW + gx];
        tin[ly][lx] = v;
    }
    __syncthreads();

    for (int idx = t; idx < 44 * 32; idx += 256) {
        int ly = idx / 32, ox = idx % 32;
        float aG = 0.f, aD = 0.f;
#pragma unroll
        for (int k = 0; k < KS; ++k) {
            float v = tin[ly][ox + k];
            aG += v * g[k];
            aD += v * dg[k];
        }
        midG[ly][ox] = aG;
        midD[ly][ox] = aD;
    }
    __syncthreads();

    float2* outp = gimg2 + (size_t)b * HH * WW;
    for (int idx = t; idx < 32 * 32; idx += 256) {
        int oy = idx / 32, ox = idx % 32;
        float a0 = 0.f, a1 = 0.f;
#pragma unroll
        for (int k = 0; k < KS; ++k) {
            a0 += midG[oy + k][ox] * dg[k];
            a1 += midD[oy + k][ox] * g[k];
        }
        int gy = ty0 + oy, gx = tx0 + ox;
        outp[gy * WW + gx] = make_float2(10.f * a0, 10.f * a1);
    }
}

// ---------------- snake optimization: 20 implicit steps, 1 wave per batch ----------------
// 64 lanes x 4 nodes/lane, all state in registers. Pentadiagonal Neumann
// iterations exchange +-2 neighbors via __shfl (no barriers, no LDS).
// Per step: 16 independent float2 bilerp-corner loads (addresses precomputed
// so they issue as one in-flight batch), then 4 shfl rounds.
__global__ __launch_bounds__(64, 1) void snake_kernel(const float2* __restrict__ gimg2,
                                                      const float* __restrict__ node_pos,
                                                      float* __restrict__ pos_out) {
    const int b = blockIdx.x;
    const int l = threadIdx.x;   // lane, nodes 4l..4l+3
    const float2* gp = gimg2 + (size_t)b * HH * WW;

    // load 4 nodes (8 contiguous floats)
    const float4* np4 = (const float4*)(node_pos + (size_t)(b * NN + 4 * l) * 2);
    float4 na = np4[0], nb = np4[1];
    float p0[4] = {na.x, na.z, nb.x, nb.z};
    float p1[4] = {na.y, na.w, nb.y, nb.w};

    // pentadiagonal rows of X for the 4 nodes
    auto Dv = [](int i, int j) -> float {
        if (i < 0 || i >= NN || j < 0 || j >= NN) return 0.f;
        if (i == j) return (i == 0 || i == NN - 1) ? 1.f : 2.f;
        int d = i - j;
        if (d == 1 || d == -1) return -1.f;
        return 0.f;
    };
    float xc[4][5];
#pragma unroll
    for (int i = 0; i < 4; ++i) {
        int n = 4 * l + i;
#pragma unroll
        for (int dj = -2; dj <= 2; ++dj) {
            int j = n + dj;
            float d2 = 0.f;
#pragma unroll
            for (int kk = -1; kk <= 1; ++kk) d2 += Dv(n, n + kk) * Dv(n + kk, j);
            xc[i][dj + 2] = 0.1f * (0.01f * Dv(n, j) + 0.01f * d2);
        }
    }

    for (int step = 0; step < 20; ++step) {
        // ---- phase 1: addresses + weights for all 16 corners ----
        int   off[4][4];
        float wgt[4][4];
#pragma unroll
        for (int i = 0; i < 4; ++i) {
            float r = fminf(fmaxf(p0[i], 0.f), (float)(HH - 1));
            float c = fminf(fmaxf(p1[i], 0.f), (float)(WW - 1));
            float rf = floorf(r), cf = floorf(c);
            int r0 = (int)rf, c0 = (int)cf;
            int r1 = min(r0 + 1, HH - 1), c1 = min(c0 + 1, WW - 1);
            float fr = r - rf, fc = c - cf;
            off[i][0] = r0 * WW + c0;
            off[i][1] = r0 * WW + c1;
            off[i][2] = r1 * WW + c0;
            off[i][3] = r1 * WW + c1;
            wgt[i][0] = (1.f - fr) * (1.f - fc);
            wgt[i][1] = (1.f - fr) * fc;
            wgt[i][2] = fr * (1.f - fc);
            wgt[i][3] = fr * fc;
        }
        // ---- phase 2: issue all 16 loads ----
        float2 v[4][4];
#pragma unroll
        for (int i = 0; i < 4; ++i)
#pragma unroll
            for (int j = 0; j < 4; ++j)
                v[i][j] = gp[off[i][j]];
        // ---- phase 3: bilerp + external force ----
        float q0[4], q1[4], s0[4], s1[4];
#pragma unroll
        for (int i = 0; i < 4; ++i) {
            float f0 = 0.f, f1 = 0.f;
#pragma unroll
            for (int j = 0; j < 4; ++j) {
                f0 += wgt[i][j] * v[i][j].x;
                f1 += wgt[i][j] * v[i][j].y;
            }
            q0[i] = p0[i] + 0.1f * f0;
            q1[i] = p1[i] + 0.1f * f1;
            s0[i] = q0[i];
            s1[i] = q1[i];
        }
        // ---- phase 4: Neumann rounds, shfl neighbor exchange ----
#pragma unroll
        for (int it = 0; it < 4; ++it) {
            float n0[8], n1[8];
            n0[0] = __shfl_up(s0[2], 1);   n0[1] = __shfl_up(s0[3], 1);
            n1[0] = __shfl_up(s1[2], 1);   n1[1] = __shfl_up(s1[3], 1);
            n0[6] = __shfl_down(s0[0], 1); n0[7] = __shfl_down(s0[1], 1);
            n1[6] = __shfl_down(s1[0], 1); n1[7] = __shfl_down(s1[1], 1);
#pragma unroll
            for (int i = 0; i < 4; ++i) { n0[2 + i] = s0[i]; n1[2 + i] = s1[i]; }
            float t0[4], t1[4];
#pragma unroll
            for (int i = 0; i < 4; ++i) {
                float a0 = 0.f, a1 = 0.f;
#pragma unroll
                for (int k = 0; k < 5; ++k) {
                    a0 += xc[i][k] * n0[i + k];
                    a1 += xc[i][k] * n1[i + k];
                }
                t0[i] = q0[i] - a0;
                t1[i] = q1[i] - a1;
            }
#pragma unroll
            for (int i = 0; i < 4; ++i) { s0[i] = t0[i]; s1[i] = t1[i]; }
        }
#pragma unroll
        for (int i = 0; i < 4; ++i) {
            p0[i] = fminf(fmaxf(s0[i], 0.f), (float)(HH - 1));
            p1[i] = fminf(fmaxf(s1[i], 0.f), (float)(WW - 1));
        }
    }

    float4 o1 = {p0[0], p1[0], p0[1], p1[1]};
    float4 o2 = {p0[2], p1[2], p0[3], p1[3]};
    float4* op = (float4*)(pos_out + (size_t)(b * NN + 4 * l) * 2);
    op[0] = o1;
    op[1] = o2;
}

// ---------------- render distance map + MSE loss (tile-binned) ----------------
__global__ __launch_bounds__(256) void render_loss_kernel(const float* __restrict__ pred,
                                                          const float* __restrict__ pos,
                                                          const float* __restrict__ widths,
                                                          float* __restrict__ out) {
    __shared__ float sl0[NN], sl1[NN], slw[NN];
    __shared__ int cnt;
    __shared__ float red[256];

    const int b    = blockIdx.x >> 8;        // 256 tiles (16x16) per batch
    const int tile = blockIdx.x & 255;
    const int ty0  = (tile >> 4) * 32;
    const int tx0  = (tile & 15) * 32;
    const int t    = threadIdx.x;

    if (t == 0) cnt = 0;
    __syncthreads();

    {   // node t relevance test against dilated tile box
        float p0 = pos[(b * NN + t) * 2 + 0];
        float p1 = pos[(b * NN + t) * 2 + 1];
        float w  = widths[b * NN + t];
        float dy = fmaxf(fmaxf((float)ty0 - p0, p0 - (float)(ty0 + 31)), 0.f);
        float dx = fmaxf(fmaxf((float)tx0 - p1, p1 - (float)(tx0 + 31)), 0.f);
        float rr = 15.f + w;
        if (dy * dy + dx * dx <= rr * rr) {
            int i = atomicAdd(&cnt, 1);
            sl0[i] = p0; sl1[i] = p1; slw[i] = w;
        }
    }
    __syncthreads();
    const int c = cnt;

    const float* pimg = pred + (size_t)b * HH * WW;
    float acc = 0.f;
#pragma unroll
    for (int i = 0; i < 4; ++i) {
        int idx = i * 256 + t;               // pixel within tile
        int oy = idx >> 5, ox = idx & 31;
        float fy = (float)(ty0 + oy);
        float fx = (float)(tx0 + ox);
        float dm = 15.0f;
        for (int j = 0; j < c; ++j) {
            float dy = fy - sl0[j];
            float dx = fx - sl1[j];
            float d = __builtin_amdgcn_sqrtf(dy * dy + dx * dx) - slw[j];
            dm = fminf(dm, d);
        }
        dm = fminf(fmaxf(dm, 0.f), 15.0f);
        float e = pimg[(ty0 + oy) * WW + (tx0 + ox)] - dm;
        acc += e * e;
    }

    red[t] = acc * (1.0f / (float)(NB * HH * WW));
    __syncthreads();
#pragma unroll
    for (int s = 128; s > 0; s >>= 1) {
        if (t < s) red[t] += red[t + s];
        __syncthreads();
    }
    if (t == 0) atomicAdd(out, red[0]);
}

extern "C" void kernel_launch(void* const* d_in, const int* in_sizes, int n_in,
                              void* d_out, int out_size, void* d_ws, size_t ws_size,
                              hipStream_t stream) {
    const float* pred     = (const float*)d_in[0];  // [8,1,512,512]
    const float* node_pos = (const float*)d_in[1];  // [8,256,2]
    const float* widths   = (const float*)d_in[2];  // [8,256]
    float* out = (float*)d_out;

    float2* gimg2  = (float2*)d_ws;                         // [8][512][512] float2 = 16 MB
    float* pos_out = (float*)d_ws + (size_t)NB * 2 * HH * WW; // [8][256][2]

    (void)hipMemsetAsync(out, 0, sizeof(float), stream);

    dim3 cgrid(WW / 32, HH / 32, NB);
    conv_kernel<<<cgrid, 256, 0, stream>>>(pred, gimg2);

    snake_kernel<<<NB, 64, 0, stream>>>(gimg2, node_pos, pos_out);

    render_loss_kernel<<<NB * 256, 256, 0, stream>>>(pred, pos_out, widths, out);
}

// Round 6
// 91.991 us; speedup vs baseline: 1.2251x; 1.0091x over previous
//
#include <hip/hip_runtime.h>
#include <math.h>

#define HH 512
#define WW 512
#define NB 8
#define NN 256
#define KR 6
#define KS 13

// ---------------- conv: separable 13x13 Gaussian-derivative, x10 ----------------
// Writes gimg interleaved as float2 (ch0, ch1) per pixel so snake's bilerp
// fetches both channels with one dwordx2 load.
__global__ __launch_bounds__(256) void conv_kernel(const float* __restrict__ pred,
                                                   float2* __restrict__ gimg2) {
    __shared__ float tin[32 + 2 * KR][32 + 2 * KR];   // 44x44
    __shared__ float midG[32 + 2 * KR][32];
    __shared__ float midD[32 + 2 * KR][32];

    const int b  = blockIdx.z;
    const int ty0 = blockIdx.y * 32;
    const int tx0 = blockIdx.x * 32;
    const int t  = threadIdx.x;

    float g[KS], dg[KS];
    float s = 0.f;
#pragma unroll
    for (int i = 0; i < KS; ++i) {
        float x = (float)(i - KR);
        g[i] = expf(-x * x / 8.f);  // std=2 -> 2*std^2 = 8
        s += g[i];
    }
#pragma unroll
    for (int i = 0; i < KS; ++i) {
        g[i] /= s;
        dg[i] = (-(float)(i - KR) / 4.f) * g[i];
    }

    const float* img = pred + (size_t)b * HH * WW;

    for (int idx = t; idx < 44 * 44; idx += 256) {
        int ly = idx / 44, lx = idx % 44;
        int gy = ty0 + ly - KR, gx = tx0 + lx - KR;
        float v = 0.f;
        if (gy >= 0 && gy < HH && gx >= 0 && gx < WW) v = img[gy * WW + gx];
        tin[ly][lx] = v;
    }
    __syncthreads();

    for (int idx = t; idx < 44 * 32; idx += 256) {
        int ly = idx / 32, ox = idx % 32;
        float aG = 0.f, aD = 0.f;
#pragma unroll
        for (int k = 0; k < KS; ++k) {
            float v = tin[ly][ox + k];
            aG += v * g[k];
            aD += v * dg[k];
        }
        midG[ly][ox] = aG;
        midD[ly][ox] = aD;
    }
    __syncthreads();

    float2* outp = gimg2 + (size_t)b * HH * WW;
    for (int idx = t; idx < 32 * 32; idx += 256) {
        int oy = idx / 32, ox = idx % 32;
        float a0 = 0.f, a1 = 0.f;
#pragma unroll
        for (int k = 0; k < KS; ++k) {
            a0 += midG[oy + k][ox] * dg[k];
            a1 += midD[oy + k][ox] * g[k];
        }
        int gy = ty0 + oy, gx = tx0 + ox;
        outp[gy * WW + gx] = make_float2(10.f * a0, 10.f * a1);
    }
}

// ---------------- snake optimization: 20 implicit steps, 1 wave per batch ----------------
// 64 lanes x 4 nodes/lane, all state in registers. Pentadiagonal Neumann
// iterations exchange +-2 neighbors via __shfl (no barriers, no LDS).
// All 16 bilerp-corner loads per step are issued via inline asm so they stay
// in ONE vmcnt group (the compiler's register heuristic otherwise splits them
// into ~4 serialized latency exposures).
__global__ __launch_bounds__(64, 1) void snake_kernel(const float2* __restrict__ gimg2,
                                                      const float* __restrict__ node_pos,
                                                      float* __restrict__ pos_out) {
    const int b = blockIdx.x;
    const int l = threadIdx.x;   // lane, nodes 4l..4l+3
    const float2* gp = gimg2 + (size_t)b * HH * WW;

    // load 4 nodes (8 contiguous floats)
    const float4* np4 = (const float4*)(node_pos + (size_t)(b * NN + 4 * l) * 2);
    float4 na = np4[0], nb = np4[1];
    float p0[4] = {na.x, na.z, nb.x, nb.z};
    float p1[4] = {na.y, na.w, nb.y, nb.w};

    // pentadiagonal rows of X for the 4 nodes
    auto Dv = [](int i, int j) -> float {
        if (i < 0 || i >= NN || j < 0 || j >= NN) return 0.f;
        if (i == j) return (i == 0 || i == NN - 1) ? 1.f : 2.f;
        int d = i - j;
        if (d == 1 || d == -1) return -1.f;
        return 0.f;
    };
    float xc[4][5];
#pragma unroll
    for (int i = 0; i < 4; ++i) {
        int n = 4 * l + i;
#pragma unroll
        for (int dj = -2; dj <= 2; ++dj) {
            int j = n + dj;
            float d2 = 0.f;
#pragma unroll
            for (int kk = -1; kk <= 1; ++kk) d2 += Dv(n, n + kk) * Dv(n + kk, j);
            xc[i][dj + 2] = 0.1f * (0.01f * Dv(n, j) + 0.01f * d2);
        }
    }

    for (int step = 0; step < 20; ++step) {
        // ---- phase 1: addresses + weights for all 16 corners ----
        const float2* ap[4][4];
        float wgt[4][4];
#pragma unroll
        for (int i = 0; i < 4; ++i) {
            float r = fminf(fmaxf(p0[i], 0.f), (float)(HH - 1));
            float c = fminf(fmaxf(p1[i], 0.f), (float)(WW - 1));
            float rf = floorf(r), cf = floorf(c);
            int r0 = (int)rf, c0 = (int)cf;
            int r1 = min(r0 + 1, HH - 1), c1 = min(c0 + 1, WW - 1);
            float fr = r - rf, fc = c - cf;
            ap[i][0] = gp + (r0 * WW + c0);
            ap[i][1] = gp + (r0 * WW + c1);
            ap[i][2] = gp + (r1 * WW + c0);
            ap[i][3] = gp + (r1 * WW + c1);
            wgt[i][0] = (1.f - fr) * (1.f - fc);
            wgt[i][1] = (1.f - fr) * fc;
            wgt[i][2] = fr * (1.f - fc);
            wgt[i][3] = fr * fc;
        }
        // ---- phase 2: issue all 16 loads in one vmcnt group (inline asm) ----
        float2 v[4][4];
#pragma unroll
        for (int i = 0; i < 4; ++i)
#pragma unroll
            for (int j = 0; j < 4; ++j)
                asm volatile("global_load_dwordx2 %0, %1, off"
                             : "=v"(v[i][j]) : "v"(ap[i][j]));
        asm volatile("s_waitcnt vmcnt(0)" ::: "memory");
        __builtin_amdgcn_sched_barrier(0);   // rule #18: keep consumers below the wait
        // ---- phase 3: bilerp + external force ----
        float q0[4], q1[4], s0[4], s1[4];
#pragma unroll
        for (int i = 0; i < 4; ++i) {
            float f0 = 0.f, f1 = 0.f;
#pragma unroll
            for (int j = 0; j < 4; ++j) {
                f0 += wgt[i][j] * v[i][j].x;
                f1 += wgt[i][j] * v[i][j].y;
            }
            q0[i] = p0[i] + 0.1f * f0;
            q1[i] = p1[i] + 0.1f * f1;
            s0[i] = q0[i];
            s1[i] = q1[i];
        }
        // ---- phase 4: Neumann rounds, shfl neighbor exchange ----
#pragma unroll
        for (int it = 0; it < 4; ++it) {
            float n0[8], n1[8];
            n0[0] = __shfl_up(s0[2], 1);   n0[1] = __shfl_up(s0[3], 1);
            n1[0] = __shfl_up(s1[2], 1);   n1[1] = __shfl_up(s1[3], 1);
            n0[6] = __shfl_down(s0[0], 1); n0[7] = __shfl_down(s0[1], 1);
            n1[6] = __shfl_down(s1[0], 1); n1[7] = __shfl_down(s1[1], 1);
#pragma unroll
            for (int i = 0; i < 4; ++i) { n0[2 + i] = s0[i]; n1[2 + i] = s1[i]; }
            float t0[4], t1[4];
#pragma unroll
            for (int i = 0; i < 4; ++i) {
                float a0 = 0.f, a1 = 0.f;
#pragma unroll
                for (int k = 0; k < 5; ++k) {
                    a0 += xc[i][k] * n0[i + k];
                    a1 += xc[i][k] * n1[i + k];
                }
                t0[i] = q0[i] - a0;
                t1[i] = q1[i] - a1;
            }
#pragma unroll
            for (int i = 0; i < 4; ++i) { s0[i] = t0[i]; s1[i] = t1[i]; }
        }
#pragma unroll
        for (int i = 0; i < 4; ++i) {
            p0[i] = fminf(fmaxf(s0[i], 0.f), (float)(HH - 1));
            p1[i] = fminf(fmaxf(s1[i], 0.f), (float)(WW - 1));
        }
    }

    float4 o1 = {p0[0], p1[0], p0[1], p1[1]};
    float4 o2 = {p0[2], p1[2], p0[3], p1[3]};
    float4* op = (float4*)(pos_out + (size_t)(b * NN + 4 * l) * 2);
    op[0] = o1;
    op[1] = o2;
}

// ---------------- render distance map + MSE loss (tile-binned) ----------------
__global__ __launch_bounds__(256) void render_loss_kernel(const float* __restrict__ pred,
                                                          const float* __restrict__ pos,
                                                          const float* __restrict__ widths,
                                                          float* __restrict__ out) {
    __shared__ float sl0[NN], sl1[NN], slw[NN];
    __shared__ int cnt;
    __shared__ float red[256];

    const int b    = blockIdx.x >> 8;        // 256 tiles (16x16) per batch
    const int tile = blockIdx.x & 255;
    const int ty0  = (tile >> 4) * 32;
    const int tx0  = (tile & 15) * 32;
    const int t    = threadIdx.x;

    if (t == 0) cnt = 0;
    __syncthreads();

    {   // node t relevance test against dilated tile box
        float p0 = pos[(b * NN + t) * 2 + 0];
        float p1 = pos[(b * NN + t) * 2 + 1];
        float w  = widths[b * NN + t];
        float dy = fmaxf(fmaxf((float)ty0 - p0, p0 - (float)(ty0 + 31)), 0.f);
        float dx = fmaxf(fmaxf((float)tx0 - p1, p1 - (float)(tx0 + 31)), 0.f);
        float rr = 15.f + w;
        if (dy * dy + dx * dx <= rr * rr) {
            int i = atomicAdd(&cnt, 1);
            sl0[i] = p0; sl1[i] = p1; slw[i] = w;
        }
    }
    __syncthreads();
    const int c = cnt;

    const float* pimg = pred + (size_t)b * HH * WW;
    float acc = 0.f;
#pragma unroll
    for (int i = 0; i < 4; ++i) {
        int idx = i * 256 + t;               // pixel within tile
        int oy = idx >> 5, ox = idx & 31;
        float fy = (float)(ty0 + oy);
        float fx = (float)(tx0 + ox);
        float dm = 15.0f;
        for (int j = 0; j < c; ++j) {
            float dy = fy - sl0[j];
            float dx = fx - sl1[j];
            float d = __builtin_amdgcn_sqrtf(dy * dy + dx * dx) - slw[j];
            dm = fminf(dm, d);
        }
        dm = fminf(fmaxf(dm, 0.f), 15.0f);
        float e = pimg[(ty0 + oy) * WW + (tx0 + ox)] - dm;
        acc += e * e;
    }

    red[t] = acc * (1.0f / (float)(NB * HH * WW));
    __syncthreads();
#pragma unroll
    for (int s = 128; s > 0; s >>= 1) {
        if (t < s) red[t] += red[t + s];
        __syncthreads();
    }
    if (t == 0) atomicAdd(out, red[0]);
}

extern "C" void kernel_launch(void* const* d_in, const int* in_sizes, int n_in,
                              void* d_out, int out_size, void* d_ws, size_t ws_size,
                              hipStream_t stream) {
    const float* pred     = (const float*)d_in[0];  // [8,1,512,512]
    const float* node_pos = (const float*)d_in[1];  // [8,256,2]
    const float* widths   = (const float*)d_in[2];  // [8,256]
    float* out = (float*)d_out;

    float2* gimg2  = (float2*)d_ws;                         // [8][512][512] float2 = 16 MB
    float* pos_out = (float*)d_ws + (size_t)NB * 2 * HH * WW; // [8][256][2]

    (void)hipMemsetAsync(out, 0, sizeof(float), stream);

    dim3 cgrid(WW / 32, HH / 32, NB);
    conv_kernel<<<cgrid, 256, 0, stream>>>(pred, gimg2);

    snake_kernel<<<NB, 64, 0, stream>>>(gimg2, node_pos, pos_out);

    render_loss_kernel<<<NB * 256, 256, 0, stream>>>(pred, pos_out, widths, out);
}

// Round 7
// 74.804 us; speedup vs baseline: 1.5066x; 1.2297x over previous
//
#include <hip/hip_runtime.h>
#include <math.h>

#define HH 512
#define WW 512
#define NB 8
#define NN 256
#define KR 6
#define KS 13

// ---- compile-time 17-diagonal band of M = I - X + X^2 - X^3 + X^4,
//      X = STEPSZ*(ALPHA*D + BETA*D^2).  ||X|| <= 0.02 -> truncation ~1.6e-6.
//      Same polynomial as the (verified-exact) 4-round Horner Neumann form.
struct MBand { float c[NN][17]; };

constexpr double Dd_c(int i, int j) {
    if (i < 0 || i >= NN || j < 0 || j >= NN) return 0.0;
    if (i == j) return (i == 0 || i == NN - 1) ? 1.0 : 2.0;
    int d = i - j;
    if (d == 1 || d == -1) return -1.0;
    return 0.0;
}

constexpr MBand make_mband() {
    MBand mb{};
    // banded X: xb[n][d] = X[n][n+d-2]
    double xb[NN][5] = {};
    for (int n = 0; n < NN; ++n)
        for (int d = 0; d < 5; ++d) {
            int j = n + d - 2;
            double d2 = 0.0;
            for (int k = n - 1; k <= n + 1; ++k) d2 += Dd_c(n, k) * Dd_c(k, j);
            xb[n][d] = 0.1 * (0.01 * Dd_c(n, j) + 0.01 * d2);
        }
    for (int n = 0; n < NN; ++n) {
        double acc[17] = {};
        double cur[17] = {};
        acc[8] = 1.0; cur[8] = 1.0;
        double sign = -1.0;
        for (int k = 1; k <= 4; ++k) {
            double nxt[17] = {};
            int lo = -2 * k, hi = 2 * k;
            for (int tp = lo; tp <= hi; ++tp) {
                int j = n + tp;
                double s = 0.0;
                if (j >= 0 && j < NN) {
                    for (int t = tp - 2; t <= tp + 2; ++t) {
                        if (t < -8 || t > 8) continue;
                        int m = n + t;
                        if (m < 0 || m >= NN) continue;
                        s += cur[8 + t] * xb[m][(tp - t) + 2];  // X[m][n+tp]
                    }
                }
                nxt[8 + tp] = s;
            }
            for (int q = 0; q < 17; ++q) { cur[q] = nxt[q]; acc[q] += sign * nxt[q]; }
            sign = -sign;
        }
        for (int q = 0; q < 17; ++q) mb.c[n][q] = (float)acc[q];
    }
    return mb;
}

__device__ __constant__ MBand d_mband = make_mband();

// ---------------- conv: separable 13x13 Gaussian-derivative, x10 ----------------
// 1D grid with b = blockIdx.x & 7 so all of batch b's tiles land on XCD b
// (round-robin dispatch): gimg[b] (2MB) + pred[b] (1MB) stay in that XCD's L2
// for the snake kernel, whose block b also lands on XCD b.
__global__ __launch_bounds__(256) void conv_kernel(const float* __restrict__ pred,
                                                   float2* __restrict__ gimg2) {
    __shared__ float tin[32 + 2 * KR][32 + 2 * KR];   // 44x44
    __shared__ float midG[32 + 2 * KR][32];
    __shared__ float midD[32 + 2 * KR][32];

    const int b    = blockIdx.x & 7;
    const int tile = blockIdx.x >> 3;     // 256 tiles (16x16)
    const int ty0  = (tile >> 4) * 32;
    const int tx0  = (tile & 15) * 32;
    const int t    = threadIdx.x;

    float g[KS], dg[KS];
    float s = 0.f;
#pragma unroll
    for (int i = 0; i < KS; ++i) {
        float x = (float)(i - KR);
        g[i] = expf(-x * x / 8.f);  // std=2 -> 2*std^2 = 8
        s += g[i];
    }
#pragma unroll
    for (int i = 0; i < KS; ++i) {
        g[i] /= s;
        dg[i] = (-(float)(i - KR) / 4.f) * g[i];
    }

    const float* img = pred + (size_t)b * HH * WW;

    for (int idx = t; idx < 44 * 44; idx += 256) {
        int ly = idx / 44, lx = idx % 44;
        int gy = ty0 + ly - KR, gx = tx0 + lx - KR;
        float v = 0.f;
        if (gy >= 0 && gy < HH && gx >= 0 && gx < WW) v = img[gy * WW + gx];
        tin[ly][lx] = v;
    }
    __syncthreads();

    for (int idx = t; idx < 44 * 32; idx += 256) {
        int ly = idx / 32, ox = idx % 32;
        float aG = 0.f, aD = 0.f;
#pragma unroll
        for (int k = 0; k < KS; ++k) {
            float v = tin[ly][ox + k];
            aG += v * g[k];
            aD += v * dg[k];
        }
        midG[ly][ox] = aG;
        midD[ly][ox] = aD;
    }
    __syncthreads();

    float2* outp = gimg2 + (size_t)b * HH * WW;
    for (int idx = t; idx < 32 * 32; idx += 256) {
        int oy = idx / 32, ox = idx % 32;
        float a0 = 0.f, a1 = 0.f;
#pragma unroll
        for (int k = 0; k < KS; ++k) {
            a0 += midG[oy + k][ox] * dg[k];
            a1 += midD[oy + k][ox] * g[k];
        }
        int gy = ty0 + oy, gx = tx0 + ox;
        outp[gy * WW + gx] = make_float2(10.f * a0, 10.f * a1);
    }
}

// ---------------- snake optimization: 20 implicit steps, 1 wave per batch ----------------
// 64 lanes x 4 nodes/lane, all state in registers. Implicit-step matrix applied
// as ONE 17-diagonal band product per step: one parallel batch of 32 shfls
// (+-1,+-2 lanes) then 17-tap dots. Out-of-range band coeffs are exactly zero,
// so clamped wave-edge shfl values are annihilated.
__global__ __launch_bounds__(64, 1) void snake_kernel(const float2* __restrict__ gimg2,
                                                      const float* __restrict__ node_pos,
                                                      float* __restrict__ pos_out) {
    const int b = blockIdx.x;
    const int l = threadIdx.x;   // lane, nodes 4l..4l+3
    const float2* gp = gimg2 + (size_t)b * HH * WW;

    // load 4 nodes (8 contiguous floats)
    const float4* np4 = (const float4*)(node_pos + (size_t)(b * NN + 4 * l) * 2);
    float4 na = np4[0], nb = np4[1];
    float p0[4] = {na.x, na.z, nb.x, nb.z};
    float p1[4] = {na.y, na.w, nb.y, nb.w};

    // band coefficients for this lane's 4 nodes -> registers
    float mb[4][17];
#pragma unroll
    for (int i = 0; i < 4; ++i)
#pragma unroll
        for (int t = 0; t < 17; ++t)
            mb[i][t] = d_mband.c[4 * l + i][t];

    for (int step = 0; step < 20; ++step) {
        // ---- phase 1: addresses + weights for all 16 corners ----
        const float2* ap[4][4];
        float wgt[4][4];
#pragma unroll
        for (int i = 0; i < 4; ++i) {
            float r = fminf(fmaxf(p0[i], 0.f), (float)(HH - 1));
            float c = fminf(fmaxf(p1[i], 0.f), (float)(WW - 1));
            float rf = floorf(r), cf = floorf(c);
            int r0 = (int)rf, c0 = (int)cf;
            int r1 = min(r0 + 1, HH - 1), c1 = min(c0 + 1, WW - 1);
            float fr = r - rf, fc = c - cf;
            ap[i][0] = gp + (r0 * WW + c0);
            ap[i][1] = gp + (r0 * WW + c1);
            ap[i][2] = gp + (r1 * WW + c0);
            ap[i][3] = gp + (r1 * WW + c1);
            wgt[i][0] = (1.f - fr) * (1.f - fc);
            wgt[i][1] = (1.f - fr) * fc;
            wgt[i][2] = fr * (1.f - fc);
            wgt[i][3] = fr * fc;
        }
        // ---- phase 2: issue all 16 loads in one vmcnt group (inline asm) ----
        float2 v[4][4];
#pragma unroll
        for (int i = 0; i < 4; ++i)
#pragma unroll
            for (int j = 0; j < 4; ++j)
                asm volatile("global_load_dwordx2 %0, %1, off"
                             : "=v"(v[i][j]) : "v"(ap[i][j]));
        asm volatile("s_waitcnt vmcnt(0)" ::: "memory");
        __builtin_amdgcn_sched_barrier(0);   // rule #18: keep consumers below the wait
        // ---- phase 3: bilerp + external force ----
        float q0[4], q1[4];
#pragma unroll
        for (int i = 0; i < 4; ++i) {
            float f0 = 0.f, f1 = 0.f;
#pragma unroll
            for (int j = 0; j < 4; ++j) {
                f0 += wgt[i][j] * v[i][j].x;
                f1 += wgt[i][j] * v[i][j].y;
            }
            q0[i] = p0[i] + 0.1f * f0;
            q1[i] = p1[i] + 0.1f * f1;
        }
        // ---- phase 4: gather 20-node q window (one parallel shfl batch) ----
        float qe0[20], qe1[20];
#pragma unroll
        for (int i = 0; i < 4; ++i) {
            qe0[i]      = __shfl_up(q0[i], 2);
            qe1[i]      = __shfl_up(q1[i], 2);
            qe0[4 + i]  = __shfl_up(q0[i], 1);
            qe1[4 + i]  = __shfl_up(q1[i], 1);
            qe0[8 + i]  = q0[i];
            qe1[8 + i]  = q1[i];
            qe0[12 + i] = __shfl_down(q0[i], 1);
            qe1[12 + i] = __shfl_down(q1[i], 1);
            qe0[16 + i] = __shfl_down(q0[i], 2);
            qe1[16 + i] = __shfl_down(q1[i], 2);
        }
        // ---- phase 5: 17-tap band dot per node + clip ----
#pragma unroll
        for (int i = 0; i < 4; ++i) {
            float a0 = 0.f, a1 = 0.f;
#pragma unroll
            for (int t = 0; t < 17; ++t) {
                a0 += mb[i][t] * qe0[i + t];
                a1 += mb[i][t] * qe1[i + t];
            }
            p0[i] = fminf(fmaxf(a0, 0.f), (float)(HH - 1));
            p1[i] = fminf(fmaxf(a1, 0.f), (float)(WW - 1));
        }
    }

    float4 o1 = {p0[0], p1[0], p0[1], p1[1]};
    float4 o2 = {p0[2], p1[2], p0[3], p1[3]};
    float4* op = (float4*)(pos_out + (size_t)(b * NN + 4 * l) * 2);
    op[0] = o1;
    op[1] = o2;
}

// ---------------- render distance map + MSE loss (tile-binned) ----------------
__global__ __launch_bounds__(256) void render_loss_kernel(const float* __restrict__ pred,
                                                          const float* __restrict__ pos,
                                                          const float* __restrict__ widths,
                                                          float* __restrict__ out) {
    __shared__ float sl0[NN], sl1[NN], slw[NN];
    __shared__ int cnt;
    __shared__ float red[256];

    const int b    = blockIdx.x & 7;         // XCD-local: batch b tiles on XCD b
    const int tile = blockIdx.x >> 3;        // 256 tiles (16x16) per batch
    const int ty0  = (tile >> 4) * 32;
    const int tx0  = (tile & 15) * 32;
    const int t    = threadIdx.x;

    if (t == 0) cnt = 0;
    __syncthreads();

    {   // node t relevance test against dilated tile box
        float p0 = pos[(b * NN + t) * 2 + 0];
        float p1 = pos[(b * NN + t) * 2 + 1];
        float w  = widths[b * NN + t];
        float dy = fmaxf(fmaxf((float)ty0 - p0, p0 - (float)(ty0 + 31)), 0.f);
        float dx = fmaxf(fmaxf((float)tx0 - p1, p1 - (float)(tx0 + 31)), 0.f);
        float rr = 15.f + w;
        if (dy * dy + dx * dx <= rr * rr) {
            int i = atomicAdd(&cnt, 1);
            sl0[i] = p0; sl1[i] = p1; slw[i] = w;
        }
    }
    __syncthreads();
    const int c = cnt;

    const float* pimg = pred + (size_t)b * HH * WW;
    float acc = 0.f;
#pragma unroll
    for (int i = 0; i < 4; ++i) {
        int idx = i * 256 + t;               // pixel within tile
        int oy = idx >> 5, ox = idx & 31;
        float fy = (float)(ty0 + oy);
        float fx = (float)(tx0 + ox);
        float dm = 15.0f;
        for (int j = 0; j < c; ++j) {
            float dy = fy - sl0[j];
            float dx = fx - sl1[j];
            float d = __builtin_amdgcn_sqrtf(dy * dy + dx * dx) - slw[j];
            dm = fminf(dm, d);
        }
        dm = fminf(fmaxf(dm, 0.f), 15.0f);
        float e = pimg[(ty0 + oy) * WW + (tx0 + ox)] - dm;
        acc += e * e;
    }

    red[t] = acc * (1.0f / (float)(NB * HH * WW));
    __syncthreads();
#pragma unroll
    for (int s = 128; s > 0; s >>= 1) {
        if (t < s) red[t] += red[t + s];
        __syncthreads();
    }
    if (t == 0) atomicAdd(out, red[0]);
}

extern "C" void kernel_launch(void* const* d_in, const int* in_sizes, int n_in,
                              void* d_out, int out_size, void* d_ws, size_t ws_size,
                              hipStream_t stream) {
    const float* pred     = (const float*)d_in[0];  // [8,1,512,512]
    const float* node_pos = (const float*)d_in[1];  // [8,256,2]
    const float* widths   = (const float*)d_in[2];  // [8,256]
    float* out = (float*)d_out;

    float2* gimg2  = (float2*)d_ws;                         // [8][512][512] float2 = 16 MB
    float* pos_out = (float*)d_ws + (size_t)NB * 2 * HH * WW; // [8][256][2]

    (void)hipMemsetAsync(out, 0, sizeof(float), stream);

    conv_kernel<<<NB * 256, 256, 0, stream>>>(pred, gimg2);

    snake_kernel<<<NB, 64, 0, stream>>>(gimg2, node_pos, pos_out);

    render_loss_kernel<<<NB * 256, 256, 0, stream>>>(pred, pos_out, widths, out);
}

// Round 8
// 69.768 us; speedup vs baseline: 1.6153x; 1.0722x over previous
//
#include <hip/hip_runtime.h>
#include <math.h>

#define HH 512
#define WW 512
#define NB 8
#define NN 256
#define KR 6
#define KS 13

// ---- compile-time 17-diagonal band of M = I - X + X^2 - X^3 + X^4,
//      X = STEPSZ*(ALPHA*D + BETA*D^2).  ||X|| <= 0.02 -> truncation ~1.6e-6.
struct MBand { float c[NN][17]; };

constexpr double Dd_c(int i, int j) {
    if (i < 0 || i >= NN || j < 0 || j >= NN) return 0.0;
    if (i == j) return (i == 0 || i == NN - 1) ? 1.0 : 2.0;
    int d = i - j;
    if (d == 1 || d == -1) return -1.0;
    return 0.0;
}

constexpr MBand make_mband() {
    MBand mb{};
    double xb[NN][5] = {};
    for (int n = 0; n < NN; ++n)
        for (int d = 0; d < 5; ++d) {
            int j = n + d - 2;
            double d2 = 0.0;
            for (int k = n - 1; k <= n + 1; ++k) d2 += Dd_c(n, k) * Dd_c(k, j);
            xb[n][d] = 0.1 * (0.01 * Dd_c(n, j) + 0.01 * d2);
        }
    for (int n = 0; n < NN; ++n) {
        double acc[17] = {};
        double cur[17] = {};
        acc[8] = 1.0; cur[8] = 1.0;
        double sign = -1.0;
        for (int k = 1; k <= 4; ++k) {
            double nxt[17] = {};
            int lo = -2 * k, hi = 2 * k;
            for (int tp = lo; tp <= hi; ++tp) {
                int j = n + tp;
                double s = 0.0;
                if (j >= 0 && j < NN) {
                    for (int t = tp - 2; t <= tp + 2; ++t) {
                        if (t < -8 || t > 8) continue;
                        int m = n + t;
                        if (m < 0 || m >= NN) continue;
                        s += cur[8 + t] * xb[m][(tp - t) + 2];
                    }
                }
                nxt[8 + tp] = s;
            }
            for (int q = 0; q < 17; ++q) { cur[q] = nxt[q]; acc[q] += sign * nxt[q]; }
            sign = -sign;
        }
        for (int q = 0; q < 17; ++q) mb.c[n][q] = (float)acc[q];
    }
    return mb;
}

__device__ __constant__ MBand d_mband = make_mband();

// ---------------- conv: separable 13x13 Gaussian-derivative, x10 ----------------
// Also zeroes out[0] (block 0) so no separate memset dispatch is needed:
// stream order conv -> render guarantees visibility before render's atomicAdds.
__global__ __launch_bounds__(256) void conv_kernel(const float* __restrict__ pred,
                                                   float2* __restrict__ gimg2,
                                                   float* __restrict__ out) {
    __shared__ float tin[32 + 2 * KR][32 + 2 * KR];   // 44x44
    __shared__ float midG[32 + 2 * KR][32];
    __shared__ float midD[32 + 2 * KR][32];

    const int b    = blockIdx.x & 7;      // XCD-local: batch b tiles on XCD b
    const int tile = blockIdx.x >> 3;     // 256 tiles (16x16)
    const int ty0  = (tile >> 4) * 32;
    const int tx0  = (tile & 15) * 32;
    const int t    = threadIdx.x;

    if (blockIdx.x == 0 && t == 0) out[0] = 0.f;

    float g[KS], dg[KS];
    float s = 0.f;
#pragma unroll
    for (int i = 0; i < KS; ++i) {
        float x = (float)(i - KR);
        g[i] = expf(-x * x / 8.f);  // std=2 -> 2*std^2 = 8
        s += g[i];
    }
#pragma unroll
    for (int i = 0; i < KS; ++i) {
        g[i] /= s;
        dg[i] = (-(float)(i - KR) / 4.f) * g[i];
    }

    const float* img = pred + (size_t)b * HH * WW;

    for (int idx = t; idx < 44 * 44; idx += 256) {
        int ly = idx / 44, lx = idx % 44;
        int gy = ty0 + ly - KR, gx = tx0 + lx - KR;
        float v = 0.f;
        if (gy >= 0 && gy < HH && gx >= 0 && gx < WW) v = img[gy * WW + gx];
        tin[ly][lx] = v;
    }
    __syncthreads();

    for (int idx = t; idx < 44 * 32; idx += 256) {
        int ly = idx / 32, ox = idx % 32;
        float aG = 0.f, aD = 0.f;
#pragma unroll
        for (int k = 0; k < KS; ++k) {
            float v = tin[ly][ox + k];
            aG += v * g[k];
            aD += v * dg[k];
        }
        midG[ly][ox] = aG;
        midD[ly][ox] = aD;
    }
    __syncthreads();

    float2* outp = gimg2 + (size_t)b * HH * WW;
    for (int idx = t; idx < 32 * 32; idx += 256) {
        int oy = idx / 32, ox = idx % 32;
        float a0 = 0.f, a1 = 0.f;
#pragma unroll
        for (int k = 0; k < KS; ++k) {
            a0 += midG[oy + k][ox] * dg[k];
            a1 += midD[oy + k][ox] * g[k];
        }
        int gy = ty0 + oy, gx = tx0 + ox;
        outp[gy * WW + gx] = make_float2(10.f * a0, 10.f * a1);
    }
}

// ---------------- snake optimization: 20 implicit steps, 1 wave per batch ----------------
__global__ __launch_bounds__(64, 1) void snake_kernel(const float2* __restrict__ gimg2,
                                                      const float* __restrict__ node_pos,
                                                      float* __restrict__ pos_out) {
    const int b = blockIdx.x;
    const int l = threadIdx.x;   // lane, nodes 4l..4l+3
    const float2* gp = gimg2 + (size_t)b * HH * WW;

    const float4* np4 = (const float4*)(node_pos + (size_t)(b * NN + 4 * l) * 2);
    float4 na = np4[0], nb = np4[1];
    float p0[4] = {na.x, na.z, nb.x, nb.z};
    float p1[4] = {na.y, na.w, nb.y, nb.w};

    float mb[4][17];
#pragma unroll
    for (int i = 0; i < 4; ++i)
#pragma unroll
        for (int t = 0; t < 17; ++t)
            mb[i][t] = d_mband.c[4 * l + i][t];

    for (int step = 0; step < 20; ++step) {
        const float2* ap[4][4];
        float wgt[4][4];
#pragma unroll
        for (int i = 0; i < 4; ++i) {
            float r = fminf(fmaxf(p0[i], 0.f), (float)(HH - 1));
            float c = fminf(fmaxf(p1[i], 0.f), (float)(WW - 1));
            float rf = floorf(r), cf = floorf(c);
            int r0 = (int)rf, c0 = (int)cf;
            int r1 = min(r0 + 1, HH - 1), c1 = min(c0 + 1, WW - 1);
            float fr = r - rf, fc = c - cf;
            ap[i][0] = gp + (r0 * WW + c0);
            ap[i][1] = gp + (r0 * WW + c1);
            ap[i][2] = gp + (r1 * WW + c0);
            ap[i][3] = gp + (r1 * WW + c1);
            wgt[i][0] = (1.f - fr) * (1.f - fc);
            wgt[i][1] = (1.f - fr) * fc;
            wgt[i][2] = fr * (1.f - fc);
            wgt[i][3] = fr * fc;
        }
        float2 v[4][4];
#pragma unroll
        for (int i = 0; i < 4; ++i)
#pragma unroll
            for (int j = 0; j < 4; ++j)
                asm volatile("global_load_dwordx2 %0, %1, off"
                             : "=v"(v[i][j]) : "v"(ap[i][j]));
        asm volatile("s_waitcnt vmcnt(0)" ::: "memory");
        __builtin_amdgcn_sched_barrier(0);
        float q0[4], q1[4];
#pragma unroll
        for (int i = 0; i < 4; ++i) {
            float f0 = 0.f, f1 = 0.f;
#pragma unroll
            for (int j = 0; j < 4; ++j) {
                f0 += wgt[i][j] * v[i][j].x;
                f1 += wgt[i][j] * v[i][j].y;
            }
            q0[i] = p0[i] + 0.1f * f0;
            q1[i] = p1[i] + 0.1f * f1;
        }
        float qe0[20], qe1[20];
#pragma unroll
        for (int i = 0; i < 4; ++i) {
            qe0[i]      = __shfl_up(q0[i], 2);
            qe1[i]      = __shfl_up(q1[i], 2);
            qe0[4 + i]  = __shfl_up(q0[i], 1);
            qe1[4 + i]  = __shfl_up(q1[i], 1);
            qe0[8 + i]  = q0[i];
            qe1[8 + i]  = q1[i];
            qe0[12 + i] = __shfl_down(q0[i], 1);
            qe1[12 + i] = __shfl_down(q1[i], 1);
            qe0[16 + i] = __shfl_down(q0[i], 2);
            qe1[16 + i] = __shfl_down(q1[i], 2);
        }
#pragma unroll
        for (int i = 0; i < 4; ++i) {
            float a0 = 0.f, a1 = 0.f;
#pragma unroll
            for (int t = 0; t < 17; ++t) {
                a0 += mb[i][t] * qe0[i + t];
                a1 += mb[i][t] * qe1[i + t];
            }
            p0[i] = fminf(fmaxf(a0, 0.f), (float)(HH - 1));
            p1[i] = fminf(fmaxf(a1, 0.f), (float)(WW - 1));
        }
    }

    float4 o1 = {p0[0], p1[0], p0[1], p1[1]};
    float4 o2 = {p0[2], p1[2], p0[3], p1[3]};
    float4* op = (float4*)(pos_out + (size_t)(b * NN + 4 * l) * 2);
    op[0] = o1;
    op[1] = o2;
}

// ---------------- render distance map + MSE loss (tile-binned) ----------------
// Thread owns 4 CONTIGUOUS pixels (one float4 pred load); dy^2 hoisted per
// node; wave shfl reduction + one barrier + one atomicAdd per block.
__global__ __launch_bounds__(256) void render_loss_kernel(const float* __restrict__ pred,
                                                          const float* __restrict__ pos,
                                                          const float* __restrict__ widths,
                                                          float* __restrict__ out) {
    __shared__ float sl0[NN], sl1[NN], slw[NN];
    __shared__ int cnt;
    __shared__ float wred[4];

    const int b    = blockIdx.x & 7;         // XCD-local: batch b tiles on XCD b
    const int tile = blockIdx.x >> 3;        // 256 tiles (16x16) per batch
    const int ty0  = (tile >> 4) * 32;
    const int tx0  = (tile & 15) * 32;
    const int t    = threadIdx.x;

    if (t == 0) cnt = 0;
    __syncthreads();

    {   // node t relevance test against dilated tile box
        float p0 = pos[(b * NN + t) * 2 + 0];
        float p1 = pos[(b * NN + t) * 2 + 1];
        float w  = widths[b * NN + t];
        float dy = fmaxf(fmaxf((float)ty0 - p0, p0 - (float)(ty0 + 31)), 0.f);
        float dx = fmaxf(fmaxf((float)tx0 - p1, p1 - (float)(tx0 + 31)), 0.f);
        float rr = 15.f + w;
        if (dy * dy + dx * dx <= rr * rr) {
            int i = atomicAdd(&cnt, 1);
            sl0[i] = p0; sl1[i] = p1; slw[i] = w;
        }
    }
    __syncthreads();
    const int c = cnt;

    // 4 contiguous pixels: row = t>>3, cols = (t&7)*4 ..+3
    const int oy = t >> 3;
    const int ox = (t & 7) * 4;
    const float fy = (float)(ty0 + oy);
    const float fx = (float)(tx0 + ox);

    float dm0 = 15.f, dm1 = 15.f, dm2 = 15.f, dm3 = 15.f;
    for (int j = 0; j < c; ++j) {
        float dy  = fy - sl0[j];
        float dy2 = dy * dy;
        float w   = slw[j];
        float dx  = fx - sl1[j];
        dm0 = fminf(dm0, __builtin_amdgcn_sqrtf(dy2 + dx * dx) - w);
        dx += 1.f;
        dm1 = fminf(dm1, __builtin_amdgcn_sqrtf(dy2 + dx * dx) - w);
        dx += 1.f;
        dm2 = fminf(dm2, __builtin_amdgcn_sqrtf(dy2 + dx * dx) - w);
        dx += 1.f;
        dm3 = fminf(dm3, __builtin_amdgcn_sqrtf(dy2 + dx * dx) - w);
    }
    dm0 = fminf(fmaxf(dm0, 0.f), 15.f);
    dm1 = fminf(fmaxf(dm1, 0.f), 15.f);
    dm2 = fminf(fmaxf(dm2, 0.f), 15.f);
    dm3 = fminf(fmaxf(dm3, 0.f), 15.f);

    const float4 pv = *(const float4*)(pred + (size_t)b * HH * WW
                                       + (ty0 + oy) * WW + (tx0 + ox));
    float e0 = pv.x - dm0, e1 = pv.y - dm1, e2 = pv.z - dm2, e3 = pv.w - dm3;
    float acc = (e0 * e0 + e1 * e1 + e2 * e2 + e3 * e3)
              * (1.0f / (float)(NB * HH * WW));

    // wave reduce (64 lanes) then 4 partials -> one atomic
#pragma unroll
    for (int m = 1; m < 64; m <<= 1) acc += __shfl_xor(acc, m);
    if ((t & 63) == 0) wred[t >> 6] = acc;
    __syncthreads();
    if (t == 0) atomicAdd(out, wred[0] + wred[1] + wred[2] + wred[3]);
}

extern "C" void kernel_launch(void* const* d_in, const int* in_sizes, int n_in,
                              void* d_out, int out_size, void* d_ws, size_t ws_size,
                              hipStream_t stream) {
    const float* pred     = (const float*)d_in[0];  // [8,1,512,512]
    const float* node_pos = (const float*)d_in[1];  // [8,256,2]
    const float* widths   = (const float*)d_in[2];  // [8,256]
    float* out = (float*)d_out;

    float2* gimg2  = (float2*)d_ws;                           // [8][512][512] float2 = 16 MB
    float* pos_out = (float*)d_ws + (size_t)NB * 2 * HH * WW; // [8][256][2]

    conv_kernel<<<NB * 256, 256, 0, stream>>>(pred, gimg2, out);

    snake_kernel<<<NB, 64, 0, stream>>>(gimg2, node_pos, pos_out);

    render_loss_kernel<<<NB * 256, 256, 0, stream>>>(pred, pos_out, widths, out);
}